// Round 14
// baseline (1058.321 us; speedup 1.0000x reference)
//
#include <hip/hip_runtime.h>
#include <hip/hip_bf16.h>

#define B_ 8192
#define D_ 2048
#define H_ 1024
#define C_ 1000
#define NSTEP 10

typedef __attribute__((ext_vector_type(8))) short short8;
typedef __attribute__((ext_vector_type(4))) float f32x4;

__device__ __forceinline__ f32x4 mfma16x16(short8 a, short8 b, f32x4 c) {
  return __builtin_amdgcn_mfma_f32_16x16x32_bf16(a, b, c, 0, 0, 0);
}

__device__ __forceinline__ void async16(void* lds_uniform, const void* gsrc) {
  __builtin_amdgcn_global_load_lds(
      (const __attribute__((address_space(1))) void*)gsrc,
      (__attribute__((address_space(3))) void*)lds_uniform, 16, 0, 0);
}

__device__ __forceinline__ float sigm(float x) { return 1.0f / (1.0f + __expf(-x)); }
__device__ __forceinline__ float tanh_fast(float x) { return 1.0f - 2.0f / (__expf(2.0f * x) + 1.0f); }
__device__ __forceinline__ float b2f(short s) {
  union { unsigned u; float f; } v; v.u = ((unsigned)(unsigned short)s) << 16; return v.f;
}
__device__ __forceinline__ unsigned short f2us(float f) {
  __hip_bfloat16 h = __float2bfloat16(f); return *(unsigned short*)&h;
}

// swizzled LDS byte offset: row stride 128B, 16B slot XOR'd with row&7
__device__ __forceinline__ int swz(int row, int slot) {
  return (row << 7) + (((slot) ^ (row & 7)) << 4);
}

// ---------------- halt MLP for one 32-row chunk (4 waves: 2 rowgrp x 2 khalf)
// u = relu(h@h1W^T + b1) [32 hidden], p = u@h2W + b2, halt -> hbuf[row][tcol].
__device__ __forceinline__ void halt_rows32(
    const __hip_bfloat16* __restrict__ hb, const __hip_bfloat16* __restrict__ h1Wb,
    const float* __restrict__ h1b, const float* __restrict__ h2W,
    const float* __restrict__ h2b, float* __restrict__ hbuf, int tcol,
    int m0base, float (*part)[2][64][8]) {
  const int tid = threadIdx.x, wave = tid >> 6, lane = tid & 63;
  const int rowgrp = wave >> 1, khalf = wave & 1;
  const int m0 = m0base + rowgrp * 16;
  const int lr = lane & 15, lk = (lane >> 4) * 8;

  const __hip_bfloat16* Arow = hb + (size_t)(m0 + lr) * H_ + khalf * 512 + lk;
  const __hip_bfloat16* B0 = h1Wb + (size_t)lr * H_ + khalf * 512 + lk;
  const __hip_bfloat16* B1 = h1Wb + (size_t)(16 + lr) * H_ + khalf * 512 + lk;
  f32x4 acc0 = {}, acc1 = {};
#pragma unroll 4
  for (int kk = 0; kk < 512; kk += 32) {
    short8 a  = *(const short8*)(Arow + kk);
    short8 b0 = *(const short8*)(B0 + kk);
    short8 b1 = *(const short8*)(B1 + kk);
    acc0 = mfma16x16(a, b0, acc0);
    acc1 = mfma16x16(a, b1, acc1);
  }
#pragma unroll
  for (int q = 0; q < 4; ++q) {
    part[rowgrp][khalf][lane][q]     = acc0[q];
    part[rowgrp][khalf][lane][4 + q] = acc1[q];
  }
  __syncthreads();
  if (!khalf) {
    const float w2a = h2W[lr], w2b = h2W[16 + lr];
    const float b1a = h1b[lr], b1b = h1b[16 + lr];
    float p[4];
#pragma unroll
    for (int q = 0; q < 4; ++q) {
      const float u0 = part[rowgrp][0][lane][q]     + part[rowgrp][1][lane][q]     + b1a;
      const float u1 = part[rowgrp][0][lane][4 + q] + part[rowgrp][1][lane][4 + q] + b1b;
      p[q] = fmaxf(u0, 0.f) * w2a + fmaxf(u1, 0.f) * w2b;
    }
#pragma unroll
    for (int m = 1; m < 16; m <<= 1) {
#pragma unroll
      for (int q = 0; q < 4; ++q) p[q] += __shfl_xor(p[q], m);
    }
    if (lr == 0) {
      const float b2 = h2b[0];
#pragma unroll
      for (int q = 0; q < 4; ++q) {
        const int row = m0 + (lane >> 4) * 4 + q;
        hbuf[(size_t)row * NSTEP + tcol] = 1.f / (1.f + expf(-(p[q] + b2)));
      }
    }
  }
  __syncthreads();
}

// ---------------- merged f32->bf16 conversions (one launch) ------------------
// regions (float4 units): x | encW | gates(4HH, r/z pre-summed) | clsW(pad) | h1W
__global__ void cvt_all(const float* __restrict__ x, const float* __restrict__ encW,
                        const float* __restrict__ Wih, const float* __restrict__ Whh,
                        const float* __restrict__ clsW, const float* __restrict__ h1W,
                        __hip_bfloat16* __restrict__ xb, __hip_bfloat16* __restrict__ encWb,
                        __hip_bfloat16* __restrict__ Wc4b, __hip_bfloat16* __restrict__ clsWb,
                        __hip_bfloat16* __restrict__ h1Wb) {
  const int i = blockIdx.x * 256 + threadIdx.x;
  const int b0 = B_ * D_ / 4;                 // x
  const int b1 = b0 + H_ * D_ / 4;            // encW
  const int b2 = b1 + H_ * H_;                // gates: 4 * (H*H/4)
  const int b3 = b2 + 1024 * 1024 / 4;        // clsW (padded to 1024 rows)
  const int b4 = b3 + 32 * H_ / 4;            // h1W
  if (i >= b4) return;
  float4 v;
  __hip_bfloat16* dst;
  int di;
  if (i < b0) {
    v = ((const float4*)x)[i]; dst = xb; di = i;
  } else if (i < b1) {
    const int j = i - b0;
    v = ((const float4*)encW)[j]; dst = encWb; di = j;
  } else if (i < b2) {
    const int j = i - b1;
    const int per_gate = H_ * H_ / 4;
    const int gate = j / per_gate, rem = j - gate * per_gate;
    if (gate == 0) {
      float4 a = ((const float4*)Wih)[rem], b = ((const float4*)Whh)[rem];
      v = make_float4(a.x + b.x, a.y + b.y, a.z + b.z, a.w + b.w);
    } else if (gate == 1) {
      float4 a = ((const float4*)Wih)[per_gate + rem], b = ((const float4*)Whh)[per_gate + rem];
      v = make_float4(a.x + b.x, a.y + b.y, a.z + b.z, a.w + b.w);
    } else if (gate == 2) {
      v = ((const float4*)Wih)[2 * per_gate + rem];
    } else {
      v = ((const float4*)Whh)[2 * per_gate + rem];
    }
    dst = Wc4b; di = j;
  } else if (i < b3) {
    const int j = i - b2;
    v = make_float4(0.f, 0.f, 0.f, 0.f);
    if (j < C_ * H_ / 4) v = ((const float4*)clsW)[j];
    dst = clsWb; di = j;
  } else {
    const int j = i - b3;
    v = ((const float4*)h1W)[j]; dst = h1Wb; di = j;
  }
  ((ushort4*)dst)[di] = make_ushort4(f2us(v.x), f2us(v.y), f2us(v.z), f2us(v.w));
}

// ---------------- generic 128x128 bf16 GEMM, C = A[M,K] * Bt[N,K]^T ----------
template<int EPI>
__global__ __launch_bounds__(256, 2)
void gemm_bt(const __hip_bfloat16* __restrict__ A, int lda,
             const __hip_bfloat16* __restrict__ Bt, int ldb, int K,
             const float* __restrict__ bias,
             float* __restrict__ out, int out_ld, int ncol,
             const float* __restrict__ wrow) {
  __shared__ __hip_bfloat16 sA[128 * 64];
  __shared__ __hip_bfloat16 sB[128 * 64];
  const int tid = threadIdx.x;
  const int wave = tid >> 6, lane = tid & 63;
  const int m0 = blockIdx.x * 128, n0 = blockIdx.y * 128;
  const int wm = (wave >> 1) * 64, wn = (wave & 1) * 64;
  const int lr = lane & 15;
  const int g4 = lane >> 4;
  const int srow = wave * 8 + (lane >> 3);
  const int scol = ((lane & 7) ^ ((lane >> 3) & 7)) * 8;

  f32x4 acc[4][4] = {};

  const __hip_bfloat16* Asrc = A + (size_t)(m0 + srow) * lda + scol;
  const __hip_bfloat16* Bsrc = Bt + (size_t)(n0 + srow) * ldb + scol;

  for (int k0 = 0; k0 < K; k0 += 64) {
#pragma unroll
    for (int c = 0; c < 4; ++c) {
      async16((char*)sA + c * 4096 + wave * 1024, Asrc + (size_t)(c * 32) * lda + k0);
      async16((char*)sB + c * 4096 + wave * 1024, Bsrc + (size_t)(c * 32) * ldb + k0);
    }
    __syncthreads();
#pragma unroll
    for (int ks = 0; ks < 2; ++ks) {
      const int slot = ks * 4 + g4;
      short8 af[4], bfr[4];
#pragma unroll
      for (int i = 0; i < 4; ++i) {
        af[i]  = *(const short8*)((const char*)sA + swz(wm + i * 16 + lr, slot));
        bfr[i] = *(const short8*)((const char*)sB + swz(wn + i * 16 + lr, slot));
      }
#pragma unroll
      for (int i = 0; i < 4; ++i)
#pragma unroll
        for (int j = 0; j < 4; ++j)
          acc[i][j] = mfma16x16(af[i], bfr[j], acc[i][j]);
    }
    __syncthreads();
  }

  const int rbase = (lane >> 4) * 4;
  const int cbase = lane & 15;
#pragma unroll
  for (int i = 0; i < 4; ++i) {
#pragma unroll
    for (int r = 0; r < 4; ++r) {
      const int grow = m0 + wm + i * 16 + rbase + r;
      if (EPI == 1) {
        const float ws = wrow[grow];
#pragma unroll
        for (int j = 0; j < 4; ++j) {
          const int gcol = n0 + wn + j * 16 + cbase;
          if (gcol < ncol)
            out[(size_t)grow * out_ld + gcol] = acc[i][j][r] + bias[gcol] * ws;
        }
      } else {
#pragma unroll
        for (int j = 0; j < 4; ++j) {
          const int gcol = n0 + wn + j * 16 + cbase;
          out[(size_t)grow * out_ld + gcol] = acc[i][j][r] + bias[gcol];
        }
      }
    }
  }
}

// ---------------- fused 4-gate GRU GEMM (fat 16x16 tile) + halt piggyback ----
// Blocks y<16: GEMM path (R13, 72us proven). Blocks y==16: halt MLP for the
// INPUT slot (h_prev = output of previous step), 128 rows per block, running
// in the GEMM's idle CU slack. tcol = halt column in hbuf (-1 = skip).
__global__ __launch_bounds__(256, 2)
void gemm_gru(const __hip_bfloat16* __restrict__ A,    // h_old bf16 [B][H]
              const __hip_bfloat16* __restrict__ Wc4,  // [4*H][H]
              const float* __restrict__ b_ih, const float* __restrict__ b_hh,
              __hip_bfloat16* __restrict__ hnewb,      // h_new bf16 [B][H]
              const __hip_bfloat16* __restrict__ h1Wb,
              const float* __restrict__ h1b, const float* __restrict__ h2W,
              const float* __restrict__ h2b, float* __restrict__ hbuf, int tcol) {
  __shared__ __hip_bfloat16 sA[128 * 64];        // 16KB (halt path reuses 8KB)
  __shared__ __hip_bfloat16 sB[4 * 64 * 64];     // 32KB
  if (blockIdx.y == 16) {
    if (tcol >= 0) {
      float (*part)[2][64][8] = (float (*)[2][64][8])sA;
      const int band = blockIdx.x * 128;
#pragma unroll
      for (int c = 0; c < 4; ++c)
        halt_rows32(A, h1Wb, h1b, h2W, h2b, hbuf, tcol, band + c * 32, part);
    }
    return;
  }
  const int tid = threadIdx.x, wave = tid >> 6, lane = tid & 63;
  const int m0 = blockIdx.x * 128, n0 = blockIdx.y * 64;
  const int wr = wave >> 1, wc = wave & 1;
  const int lr = lane & 15;
  const int g4 = lane >> 4;
  const int srow = lane >> 3;
  const int scol = ((lane & 7) ^ ((lane >> 3) & 7)) * 8;

  f32x4 acc[4][4][2] = {};   // [m-subtile][gate][hcol-16-block]

  const __hip_bfloat16* Asrc = A + (size_t)(m0 + wave * 8 + srow) * H_ + scol;
  const __hip_bfloat16* Bsrc = Wc4 + (size_t)(n0 + wave * 8 + srow) * H_ + scol;

  for (int k0 = 0; k0 < H_; k0 += 64) {
#pragma unroll
    for (int c = 0; c < 4; ++c)
      async16((char*)sA + c * 4096 + wave * 1024, Asrc + (size_t)(c * 32) * H_ + k0);
#pragma unroll
    for (int g = 0; g < 4; ++g)
#pragma unroll
      for (int d = 0; d < 2; ++d)
        async16((char*)sB + g * 8192 + d * 4096 + wave * 1024,
                Bsrc + ((size_t)g << 20) + (size_t)(d * 32) * H_ + k0);
    __syncthreads();
#pragma unroll
    for (int ks = 0; ks < 2; ++ks) {
      const int slot = ks * 4 + g4;
      short8 af[4];
#pragma unroll
      for (int mi = 0; mi < 4; ++mi)
        af[mi] = *(const short8*)((const char*)sA + swz(wr * 64 + mi * 16 + lr, slot));
      short8 bf[4][2];
#pragma unroll
      for (int g = 0; g < 4; ++g)
#pragma unroll
        for (int hb = 0; hb < 2; ++hb)
          bf[g][hb] = *(const short8*)((const char*)sB + g * 8192
                                       + swz(wc * 32 + hb * 16 + lr, slot));
#pragma unroll
      for (int mi = 0; mi < 4; ++mi)
#pragma unroll
        for (int g = 0; g < 4; ++g)
#pragma unroll
          for (int hb = 0; hb < 2; ++hb)
            acc[mi][g][hb] = mfma16x16(af[mi], bf[g][hb], acc[mi][g][hb]);
    }
    __syncthreads();
  }

  const int rbase = (lane >> 4) * 4;
  const int cbase = lane & 15;
#pragma unroll
  for (int hb = 0; hb < 2; ++hb) {
    const int gcol = n0 + wc * 32 + hb * 16 + cbase;
    const float brz = b_ih[gcol] + b_hh[gcol];
    const float bzz = b_ih[H_ + gcol] + b_hh[H_ + gcol];
    const float bin = b_ih[2 * H_ + gcol];
    const float bhn = b_hh[2 * H_ + gcol];
#pragma unroll
    for (int mi = 0; mi < 4; ++mi) {
#pragma unroll
      for (int r = 0; r < 4; ++r) {
        const int grow = m0 + wr * 64 + mi * 16 + rbase + r;
        const size_t idx = (size_t)grow * H_ + gcol;
        const float rg = sigm(acc[mi][0][hb][r] + brz);
        const float zg = sigm(acc[mi][1][hb][r] + bzz);
        const float ng = tanh_fast(acc[mi][2][hb][r] + bin + rg * (acc[mi][3][hb][r] + bhn));
        const float hv = b2f(*(const short*)(A + idx));
        hnewb[idx] = __float2bfloat16((1.0f - zg) * ng + zg * hv);
      }
    }
  }
}

// ---------------- standalone halt for the last slot --------------------------
__global__ __launch_bounds__(256, 4)
void halt_last(const __hip_bfloat16* __restrict__ hb,
               const __hip_bfloat16* __restrict__ h1Wb,
               const float* __restrict__ h1b, const float* __restrict__ h2W,
               const float* __restrict__ h2b, float* __restrict__ hbuf, int tcol) {
  __shared__ float part[2][2][64][8];
  halt_rows32(hb, h1Wb, h1b, h2W, h2b, hbuf, tcol, blockIdx.x * 32, part);
}

// ---------------- LayerNorm + exact GELU (bf16 out only) ---------------------
__global__ void ln_gelu(const float* __restrict__ z, const float* __restrict__ g,
                        const float* __restrict__ bta, __hip_bfloat16* __restrict__ hb) {
  const int row = blockIdx.x, t = threadIdx.x;
  __shared__ float rs[4], rs2[4];
  float4 v = ((const float4*)(z + (size_t)row * H_))[t];
  float s = v.x + v.y + v.z + v.w;
  float s2 = v.x * v.x + v.y * v.y + v.z * v.z + v.w * v.w;
#pragma unroll
  for (int off = 32; off; off >>= 1) {
    s += __shfl_down(s, off);
    s2 += __shfl_down(s2, off);
  }
  if ((t & 63) == 0) { rs[t >> 6] = s; rs2[t >> 6] = s2; }
  __syncthreads();
  const float mu = (rs[0] + rs[1] + rs[2] + rs[3]) * (1.0f / H_);
  const float var = (rs2[0] + rs2[1] + rs2[2] + rs2[3]) * (1.0f / H_) - mu * mu;
  const float rstd = rsqrtf(var + 1e-5f);
  float4 gg = ((const float4*)g)[t];
  float4 bb = ((const float4*)bta)[t];
  float o[4], res[4];
  o[0] = (v.x - mu) * rstd * gg.x + bb.x;
  o[1] = (v.y - mu) * rstd * gg.y + bb.y;
  o[2] = (v.z - mu) * rstd * gg.z + bb.z;
  o[3] = (v.w - mu) * rstd * gg.w + bb.w;
#pragma unroll
  for (int k = 0; k < 4; ++k)
    res[k] = 0.5f * o[k] * (1.0f + erff(o[k] * 0.70710678118654752f));
  ((ushort4*)(hb + (size_t)row * H_))[t] =
      make_ushort4(f2us(res[0]), f2us(res[1]), f2us(res[2]), f2us(res[3]));
}

// ---------------- PonderNet recurrence (per-row scalar) ----------------------
__global__ void ponder_rec(const float* __restrict__ hbuf,
                           float* __restrict__ out_hd, float* __restrict__ out_es,
                           float* __restrict__ out_cu, float* __restrict__ wsum) {
  const int row = blockIdx.x * 256 + threadIdx.x;
  const float* hp = hbuf + (size_t)row * NSTEP;
  float c = 0.f, ps = 0.f, es = 0.f;
  float hd[NSTEP];
#pragma unroll
  for (int t = 0; t < NSTEP; ++t) {
    const float halt = hp[t];
    const float pt = halt * expf(c);
    float w;
    if (t == NSTEP - 1) {
      w = pt + fmaxf(1.f - (ps + pt), 0.f);
    } else {
      w = pt;
      c += logf(1.f - halt + 1e-8f);
      ps += pt;
    }
    es += w * (float)(t + 1);
    hd[t] = w;
  }
#pragma unroll
  for (int t = 0; t < NSTEP; ++t) out_hd[(size_t)row * NSTEP + t] = hd[t];
  out_es[row] = es;
  out_cu[row] = es * (1.0f / NSTEP);
  wsum[row] = ps + hd[NSTEP - 1];
}

// ---------------- final weighted sum: hw = sum_t w_t * h_t -------------------
__global__ void hw_final(const __hip_bfloat16* __restrict__ hstack,  // [11][B][H], slots 1..10
                         const float* __restrict__ out_hd,           // [B][10]
                         __hip_bfloat16* __restrict__ hwb) {
  const int t = threadIdx.x;
  const int row = blockIdx.x * 4 + (t >> 6);
  const int c0 = (t & 63) * 16;
  const float* hd = out_hd + (size_t)row * NSTEP;
  float accv[16] = {};
#pragma unroll
  for (int s = 0; s < NSTEP; ++s) {
    const float w = hd[s];
    const short8* p = (const short8*)(hstack + ((size_t)(s + 1) * B_ + row) * H_ + c0);
    short8 a0 = p[0], a1 = p[1];
#pragma unroll
    for (int q = 0; q < 8; ++q) accv[q] += w * b2f(a0[q]);
#pragma unroll
    for (int q = 0; q < 8; ++q) accv[8 + q] += w * b2f(a1[q]);
  }
  short8 r0, r1;
#pragma unroll
  for (int q = 0; q < 8; ++q) { r0[q] = (short)f2us(accv[q]); r1[q] = (short)f2us(accv[8 + q]); }
  short8* dst = (short8*)(hwb + (size_t)row * H_ + c0);
  dst[0] = r0; dst[1] = r1;
}

// ---------------- softmax + confidence ---------------------------------------
__global__ void finalize(const float* __restrict__ wl, const float* __restrict__ es,
                         float* __restrict__ probs, float* __restrict__ conf,
                         float* __restrict__ sconf) {
  const int row = blockIdx.x, t = threadIdx.x;
  __shared__ float red[4], red2[4];
  float4 v = make_float4(-1e30f, -1e30f, -1e30f, -1e30f);
  float m = -1e30f;
  if (t < 250) {
    v = ((const float4*)(wl + (size_t)row * C_))[t];
    m = fmaxf(fmaxf(v.x, v.y), fmaxf(v.z, v.w));
  }
#pragma unroll
  for (int off = 32; off; off >>= 1) m = fmaxf(m, __shfl_down(m, off));
  if ((t & 63) == 0) red[t >> 6] = m;
  __syncthreads();
  m = fmaxf(fmaxf(red[0], red[1]), fmaxf(red[2], red[3]));
  float4 e = make_float4(0.f, 0.f, 0.f, 0.f);
  float s = 0.f;
  if (t < 250) {
    e.x = expf(v.x - m); e.y = expf(v.y - m); e.z = expf(v.z - m); e.w = expf(v.w - m);
    s = e.x + e.y + e.z + e.w;
  }
#pragma unroll
  for (int off = 32; off; off >>= 1) s += __shfl_down(s, off);
  if ((t & 63) == 0) red2[t >> 6] = s;
  __syncthreads();
  s = red2[0] + red2[1] + red2[2] + red2[3];
  const float inv = 1.0f / s;
  if (t < 250)
    ((float4*)(probs + (size_t)row * C_))[t] = make_float4(e.x * inv, e.y * inv, e.z * inv, e.w * inv);
  if (t == 0) {
    sconf[row] = inv;
    conf[row] = 0.7f * inv + 0.3f * (1.0f - es[row] * (1.0f / NSTEP));
  }
}

// ---------------- host orchestration -----------------------------------------
extern "C" void kernel_launch(void* const* d_in, const int* in_sizes, int n_in,
                              void* d_out, int out_size, void* d_ws, size_t ws_size,
                              hipStream_t stream) {
  (void)in_sizes; (void)n_in; (void)out_size; (void)ws_size;
  const float* x     = (const float*)d_in[0];
  const float* enc_W = (const float*)d_in[1];
  const float* enc_b = (const float*)d_in[2];
  const float* ln_g  = (const float*)d_in[3];
  const float* ln_b  = (const float*)d_in[4];
  const float* W_ih  = (const float*)d_in[5];
  const float* W_hh  = (const float*)d_in[6];
  const float* b_ih  = (const float*)d_in[7];
  const float* b_hh  = (const float*)d_in[8];
  const float* cls_W = (const float*)d_in[9];
  const float* cls_b = (const float*)d_in[10];
  const float* h1_W  = (const float*)d_in[11];
  const float* h1_b  = (const float*)d_in[12];
  const float* h2_W  = (const float*)d_in[13];
  const float* h2_b  = (const float*)d_in[14];

  char* wsp = (char*)d_ws;
  auto carve = [&](size_t n) { char* p = wsp; wsp += (n + 255) & ~(size_t)255; return p; };
  __hip_bfloat16* Wc4b   = (__hip_bfloat16*)carve((size_t)4 * H_ * H_ * 2);
  __hip_bfloat16* clsWb  = (__hip_bfloat16*)carve((size_t)1024 * 1024 * 2);
  __hip_bfloat16* encWb  = (__hip_bfloat16*)carve((size_t)H_ * D_ * 2);
  __hip_bfloat16* h1Wb   = (__hip_bfloat16*)carve((size_t)32 * H_ * 2);
  __hip_bfloat16* hstack = (__hip_bfloat16*)carve((size_t)(NSTEP + 1) * B_ * H_ * 2);
  float* wsum = (float*)carve((size_t)B_ * 4);
  float* hbuf = (float*)carve((size_t)B_ * NSTEP * 4);

  const size_t SLOT = (size_t)B_ * H_;  // elements per hstack slot
  float* z            = (float*)(hstack + SLOT);        // slots 1-2 (32MB fp32)
  __hip_bfloat16* xb  = hstack + 3 * SLOT;              // slots 3-4 (32MB bf16)
  __hip_bfloat16* hwb = hstack;                         // slot 0, reused at end

  float* out = (float*)d_out;
  float* out_wl    = out;
  float* out_probs = out + (size_t)B_ * C_;
  float* out_conf  = out + (size_t)2 * B_ * C_;
  float* out_sconf = out_conf + B_;
  float* out_es    = out_sconf + B_;
  float* out_hd    = out_es + B_;
  float* out_cu    = out_hd + (size_t)B_ * NSTEP;

  dim3 blk(256);
  // merged conversions (x, encW, gates, clsW-pad, h1W) in one launch
  {
    const int total = B_ * D_ / 4 + H_ * D_ / 4 + H_ * H_ + 1024 * 1024 / 4 + 32 * H_ / 4;
    cvt_all<<<(total + 255) / 256, blk, 0, stream>>>(
        x, enc_W, W_ih, W_hh, cls_W, h1_W, xb, encWb, Wc4b, clsWb, h1Wb);
  }

  // encoder: GEMM -> z (fp32, slots 1-2), LN+GELU -> h0 (slot 0, bf16)
  gemm_bt<0><<<dim3(B_ / 128, H_ / 128), blk, 0, stream>>>(
      xb, D_, encWb, D_, D_, enc_b, z, H_, H_, nullptr);
  ln_gelu<<<B_, blk, 0, stream>>>(z, ln_g, ln_b, hstack);

  // 10 GRU steps; step >= 1 piggybacks halt of its INPUT slot (y==16 band)
  for (int step = 0; step < NSTEP; ++step) {
    const __hip_bfloat16* hprev = hstack + (size_t)step * SLOT;
    __hip_bfloat16* hnext = hstack + (size_t)(step + 1) * SLOT;
    gemm_gru<<<dim3(B_ / 128, 17), blk, 0, stream>>>(
        hprev, Wc4b, b_ih, b_hh, hnext, h1Wb, h1_b, h2_W, h2_b, hbuf, step - 1);
  }
  // halt for the last slot (10)
  halt_last<<<B_ / 32, blk, 0, stream>>>(
      hstack + (size_t)NSTEP * SLOT, h1Wb, h1_b, h2_W, h2_b, hbuf, NSTEP - 1);

  ponder_rec<<<B_ / 256, blk, 0, stream>>>(hbuf, out_hd, out_es, out_cu, wsum);

  // hw = sum_t w_t h_t  (reads slots 1..10, writes slot 0)
  hw_final<<<B_ / 4, blk, 0, stream>>>(hstack, out_hd, hwb);

  // weighted logits: hw @ cls_W^T + cls_b * wsum
  gemm_bt<1><<<dim3(B_ / 128, 1024 / 128), blk, 0, stream>>>(
      hwb, H_, clsWb, H_, H_, cls_b, out_wl, C_, C_, wsum);

  finalize<<<B_, blk, 0, stream>>>(out_wl, out_es, out_probs, out_conf, out_sconf);
}

// Round 15
// 899.003 us; speedup vs baseline: 1.1772x; 1.1772x over previous
//
#include <hip/hip_runtime.h>
#include <hip/hip_bf16.h>

#define B_ 8192
#define D_ 2048
#define H_ 1024
#define C_ 1000
#define NSTEP 10

typedef __attribute__((ext_vector_type(8))) short short8;
typedef __attribute__((ext_vector_type(4))) float f32x4;

__device__ __forceinline__ f32x4 mfma16x16(short8 a, short8 b, f32x4 c) {
  return __builtin_amdgcn_mfma_f32_16x16x32_bf16(a, b, c, 0, 0, 0);
}

__device__ __forceinline__ void async16(void* lds_uniform, const void* gsrc) {
  __builtin_amdgcn_global_load_lds(
      (const __attribute__((address_space(1))) void*)gsrc,
      (__attribute__((address_space(3))) void*)lds_uniform, 16, 0, 0);
}

__device__ __forceinline__ float sigm(float x) { return 1.0f / (1.0f + __expf(-x)); }
__device__ __forceinline__ float tanh_fast(float x) { return 1.0f - 2.0f / (__expf(2.0f * x) + 1.0f); }
__device__ __forceinline__ float b2f(short s) {
  union { unsigned u; float f; } v; v.u = ((unsigned)(unsigned short)s) << 16; return v.f;
}
__device__ __forceinline__ unsigned short f2us(float f) {
  __hip_bfloat16 h = __float2bfloat16(f); return *(unsigned short*)&h;
}

// swizzled LDS byte offset: row stride 128B, 16B slot XOR'd with row&7
__device__ __forceinline__ int swz(int row, int slot) {
  return (row << 7) + (((slot) ^ (row & 7)) << 4);
}

// ---------------- merged f32->bf16 conversions (one launch) ------------------
__global__ void cvt_all(const float* __restrict__ x, const float* __restrict__ encW,
                        const float* __restrict__ Wih, const float* __restrict__ Whh,
                        const float* __restrict__ clsW, const float* __restrict__ h1W,
                        __hip_bfloat16* __restrict__ xb, __hip_bfloat16* __restrict__ encWb,
                        __hip_bfloat16* __restrict__ Wc4b, __hip_bfloat16* __restrict__ clsWb,
                        __hip_bfloat16* __restrict__ h1Wb) {
  const int i = blockIdx.x * 256 + threadIdx.x;
  const int b0 = B_ * D_ / 4;                 // x
  const int b1 = b0 + H_ * D_ / 4;            // encW
  const int b2 = b1 + H_ * H_;                // gates: 4 * (H*H/4)
  const int b3 = b2 + 1024 * 1024 / 4;        // clsW (padded to 1024 rows)
  const int b4 = b3 + 32 * H_ / 4;            // h1W
  if (i >= b4) return;
  float4 v;
  __hip_bfloat16* dst;
  int di;
  if (i < b0) {
    v = ((const float4*)x)[i]; dst = xb; di = i;
  } else if (i < b1) {
    const int j = i - b0;
    v = ((const float4*)encW)[j]; dst = encWb; di = j;
  } else if (i < b2) {
    const int j = i - b1;
    const int per_gate = H_ * H_ / 4;
    const int gate = j / per_gate, rem = j - gate * per_gate;
    if (gate == 0) {
      float4 a = ((const float4*)Wih)[rem], b = ((const float4*)Whh)[rem];
      v = make_float4(a.x + b.x, a.y + b.y, a.z + b.z, a.w + b.w);
    } else if (gate == 1) {
      float4 a = ((const float4*)Wih)[per_gate + rem], b = ((const float4*)Whh)[per_gate + rem];
      v = make_float4(a.x + b.x, a.y + b.y, a.z + b.z, a.w + b.w);
    } else if (gate == 2) {
      v = ((const float4*)Wih)[2 * per_gate + rem];
    } else {
      v = ((const float4*)Whh)[2 * per_gate + rem];
    }
    dst = Wc4b; di = j;
  } else if (i < b3) {
    const int j = i - b2;
    v = make_float4(0.f, 0.f, 0.f, 0.f);
    if (j < C_ * H_ / 4) v = ((const float4*)clsW)[j];
    dst = clsWb; di = j;
  } else {
    const int j = i - b3;
    v = ((const float4*)h1W)[j]; dst = h1Wb; di = j;
  }
  ((ushort4*)dst)[di] = make_ushort4(f2us(v.x), f2us(v.y), f2us(v.z), f2us(v.w));
}

// ---------------- generic 128x128 bf16 GEMM, C = A[M,K] * Bt[N,K]^T ----------
template<int EPI>
__global__ __launch_bounds__(256, 2)
void gemm_bt(const __hip_bfloat16* __restrict__ A, int lda,
             const __hip_bfloat16* __restrict__ Bt, int ldb, int K,
             const float* __restrict__ bias,
             float* __restrict__ out, int out_ld, int ncol,
             const float* __restrict__ wrow) {
  __shared__ __hip_bfloat16 sA[128 * 64];
  __shared__ __hip_bfloat16 sB[128 * 64];
  const int tid = threadIdx.x;
  const int wave = tid >> 6, lane = tid & 63;
  const int m0 = blockIdx.x * 128, n0 = blockIdx.y * 128;
  const int wm = (wave >> 1) * 64, wn = (wave & 1) * 64;
  const int lr = lane & 15;
  const int g4 = lane >> 4;
  const int srow = wave * 8 + (lane >> 3);
  const int scol = ((lane & 7) ^ ((lane >> 3) & 7)) * 8;

  f32x4 acc[4][4] = {};

  const __hip_bfloat16* Asrc = A + (size_t)(m0 + srow) * lda + scol;
  const __hip_bfloat16* Bsrc = Bt + (size_t)(n0 + srow) * ldb + scol;

  for (int k0 = 0; k0 < K; k0 += 64) {
#pragma unroll
    for (int c = 0; c < 4; ++c) {
      async16((char*)sA + c * 4096 + wave * 1024, Asrc + (size_t)(c * 32) * lda + k0);
      async16((char*)sB + c * 4096 + wave * 1024, Bsrc + (size_t)(c * 32) * ldb + k0);
    }
    __syncthreads();
#pragma unroll
    for (int ks = 0; ks < 2; ++ks) {
      const int slot = ks * 4 + g4;
      short8 af[4], bfr[4];
#pragma unroll
      for (int i = 0; i < 4; ++i) {
        af[i]  = *(const short8*)((const char*)sA + swz(wm + i * 16 + lr, slot));
        bfr[i] = *(const short8*)((const char*)sB + swz(wn + i * 16 + lr, slot));
      }
#pragma unroll
      for (int i = 0; i < 4; ++i)
#pragma unroll
        for (int j = 0; j < 4; ++j)
          acc[i][j] = mfma16x16(af[i], bfr[j], acc[i][j]);
    }
    __syncthreads();
  }

  const int rbase = (lane >> 4) * 4;
  const int cbase = lane & 15;
#pragma unroll
  for (int i = 0; i < 4; ++i) {
#pragma unroll
    for (int r = 0; r < 4; ++r) {
      const int grow = m0 + wm + i * 16 + rbase + r;
      if (EPI == 1) {
        const float ws = wrow[grow];
#pragma unroll
        for (int j = 0; j < 4; ++j) {
          const int gcol = n0 + wn + j * 16 + cbase;
          if (gcol < ncol)
            out[(size_t)grow * out_ld + gcol] = acc[i][j][r] + bias[gcol] * ws;
        }
      } else {
#pragma unroll
        for (int j = 0; j < 4; ++j) {
          const int gcol = n0 + wn + j * 16 + cbase;
          out[(size_t)grow * out_ld + gcol] = acc[i][j][r] + bias[gcol];
        }
      }
    }
  }
}

// ---------------- fused 4-gate GRU GEMM (fat 16x16 tile, R13 proven) ---------
// Wc4 = {W_r_sum, W_z_sum, W_ih_n, W_hh_n}. Block = 128 rows x 64 hcols x 4
// gates; 4 waves 2M x 2N; wave = 64 rows x 32 hcols x 4 gates.
// Per wave-K64: 24 ds_read_b128 feed 64 MFMA. 72us / ~950 TF measured.
__global__ __launch_bounds__(256, 2)
void gemm_gru(const __hip_bfloat16* __restrict__ A,    // h_old bf16 [B][H]
              const __hip_bfloat16* __restrict__ Wc4,  // [4*H][H]
              const float* __restrict__ b_ih, const float* __restrict__ b_hh,
              __hip_bfloat16* __restrict__ hnewb) {    // h_new bf16 [B][H]
  __shared__ __hip_bfloat16 sA[128 * 64];        // 16KB
  __shared__ __hip_bfloat16 sB[4 * 64 * 64];     // 32KB
  const int tid = threadIdx.x, wave = tid >> 6, lane = tid & 63;
  const int m0 = blockIdx.x * 128, n0 = blockIdx.y * 64;
  const int wr = wave >> 1, wc = wave & 1;
  const int lr = lane & 15;
  const int g4 = lane >> 4;
  const int srow = lane >> 3;
  const int scol = ((lane & 7) ^ ((lane >> 3) & 7)) * 8;

  f32x4 acc[4][4][2] = {};   // [m-subtile][gate][hcol-16-block]

  const __hip_bfloat16* Asrc = A + (size_t)(m0 + wave * 8 + srow) * H_ + scol;
  const __hip_bfloat16* Bsrc = Wc4 + (size_t)(n0 + wave * 8 + srow) * H_ + scol;

  for (int k0 = 0; k0 < H_; k0 += 64) {
#pragma unroll
    for (int c = 0; c < 4; ++c)
      async16((char*)sA + c * 4096 + wave * 1024, Asrc + (size_t)(c * 32) * H_ + k0);
#pragma unroll
    for (int g = 0; g < 4; ++g)
#pragma unroll
      for (int d = 0; d < 2; ++d)
        async16((char*)sB + g * 8192 + d * 4096 + wave * 1024,
                Bsrc + ((size_t)g << 20) + (size_t)(d * 32) * H_ + k0);
    __syncthreads();
#pragma unroll
    for (int ks = 0; ks < 2; ++ks) {
      const int slot = ks * 4 + g4;
      short8 af[4];
#pragma unroll
      for (int mi = 0; mi < 4; ++mi)
        af[mi] = *(const short8*)((const char*)sA + swz(wr * 64 + mi * 16 + lr, slot));
      short8 bf[4][2];
#pragma unroll
      for (int g = 0; g < 4; ++g)
#pragma unroll
        for (int hb = 0; hb < 2; ++hb)
          bf[g][hb] = *(const short8*)((const char*)sB + g * 8192
                                       + swz(wc * 32 + hb * 16 + lr, slot));
#pragma unroll
      for (int mi = 0; mi < 4; ++mi)
#pragma unroll
        for (int g = 0; g < 4; ++g)
#pragma unroll
          for (int hb = 0; hb < 2; ++hb)
            acc[mi][g][hb] = mfma16x16(af[mi], bf[g][hb], acc[mi][g][hb]);
    }
    __syncthreads();
  }

  const int rbase = (lane >> 4) * 4;
  const int cbase = lane & 15;
#pragma unroll
  for (int hb = 0; hb < 2; ++hb) {
    const int gcol = n0 + wc * 32 + hb * 16 + cbase;
    const float brz = b_ih[gcol] + b_hh[gcol];
    const float bzz = b_ih[H_ + gcol] + b_hh[H_ + gcol];
    const float bin = b_ih[2 * H_ + gcol];
    const float bhn = b_hh[2 * H_ + gcol];
#pragma unroll
    for (int mi = 0; mi < 4; ++mi) {
#pragma unroll
      for (int r = 0; r < 4; ++r) {
        const int grow = m0 + wr * 64 + mi * 16 + rbase + r;
        const size_t idx = (size_t)grow * H_ + gcol;
        const float rg = sigm(acc[mi][0][hb][r] + brz);
        const float zg = sigm(acc[mi][1][hb][r] + bzz);
        const float ng = tanh_fast(acc[mi][2][hb][r] + bin + rg * (acc[mi][3][hb][r] + bhn));
        const float hv = b2f(*(const short*)(A + idx));
        hnewb[idx] = __float2bfloat16((1.0f - zg) * ng + zg * hv);
      }
    }
  }
}

// ---------------- LayerNorm + exact GELU (bf16 out only) ---------------------
__global__ void ln_gelu(const float* __restrict__ z, const float* __restrict__ g,
                        const float* __restrict__ bta, __hip_bfloat16* __restrict__ hb) {
  const int row = blockIdx.x, t = threadIdx.x;
  __shared__ float rs[4], rs2[4];
  float4 v = ((const float4*)(z + (size_t)row * H_))[t];
  float s = v.x + v.y + v.z + v.w;
  float s2 = v.x * v.x + v.y * v.y + v.z * v.z + v.w * v.w;
#pragma unroll
  for (int off = 32; off; off >>= 1) {
    s += __shfl_down(s, off);
    s2 += __shfl_down(s2, off);
  }
  if ((t & 63) == 0) { rs[t >> 6] = s; rs2[t >> 6] = s2; }
  __syncthreads();
  const float mu = (rs[0] + rs[1] + rs[2] + rs[3]) * (1.0f / H_);
  const float var = (rs2[0] + rs2[1] + rs2[2] + rs2[3]) * (1.0f / H_) - mu * mu;
  const float rstd = rsqrtf(var + 1e-5f);
  float4 gg = ((const float4*)g)[t];
  float4 bb = ((const float4*)bta)[t];
  float o[4], res[4];
  o[0] = (v.x - mu) * rstd * gg.x + bb.x;
  o[1] = (v.y - mu) * rstd * gg.y + bb.y;
  o[2] = (v.z - mu) * rstd * gg.z + bb.z;
  o[3] = (v.w - mu) * rstd * gg.w + bb.w;
#pragma unroll
  for (int k = 0; k < 4; ++k)
    res[k] = 0.5f * o[k] * (1.0f + erff(o[k] * 0.70710678118654752f));
  ((ushort4*)(hb + (size_t)row * H_))[t] =
      make_ushort4(f2us(res[0]), f2us(res[1]), f2us(res[2]), f2us(res[3]));
}

// ---------------- batched halt MLP (all 10 steps in one launch) --------------
__global__ __launch_bounds__(256, 4)
void halt_mlp_all(const __hip_bfloat16* __restrict__ hstack,  // slots 1..10
                  const __hip_bfloat16* __restrict__ h1Wb,
                  const float* __restrict__ h1b, const float* __restrict__ h2W,
                  const float* __restrict__ h2b,
                  float* __restrict__ hbuf) {
  __shared__ float part[2][2][64][8];
  const int tid = threadIdx.x, wave = tid >> 6, lane = tid & 63;
  const int tstep = blockIdx.y;
  const __hip_bfloat16* hb = hstack + (size_t)(tstep + 1) * B_ * H_;
  const int rowgrp = wave >> 1, khalf = wave & 1;
  const int m0 = (blockIdx.x * 2 + rowgrp) * 16;
  const int lr = lane & 15, lk = (lane >> 4) * 8;

  const __hip_bfloat16* Arow = hb + (size_t)(m0 + lr) * H_ + khalf * 512 + lk;
  const __hip_bfloat16* B0 = h1Wb + (size_t)lr * H_ + khalf * 512 + lk;
  const __hip_bfloat16* B1 = h1Wb + (size_t)(16 + lr) * H_ + khalf * 512 + lk;
  f32x4 acc0 = {}, acc1 = {};
#pragma unroll 4
  for (int kk = 0; kk < 512; kk += 32) {
    short8 a  = *(const short8*)(Arow + kk);
    short8 b0 = *(const short8*)(B0 + kk);
    short8 b1 = *(const short8*)(B1 + kk);
    acc0 = mfma16x16(a, b0, acc0);
    acc1 = mfma16x16(a, b1, acc1);
  }
#pragma unroll
  for (int q = 0; q < 4; ++q) {
    part[rowgrp][khalf][lane][q]     = acc0[q];
    part[rowgrp][khalf][lane][4 + q] = acc1[q];
  }
  __syncthreads();
  if (khalf) return;

  const float w2a = h2W[lr], w2b = h2W[16 + lr];
  const float b1a = h1b[lr], b1b = h1b[16 + lr];
  float p[4];
#pragma unroll
  for (int q = 0; q < 4; ++q) {
    const float u0 = part[rowgrp][0][lane][q]     + part[rowgrp][1][lane][q]     + b1a;
    const float u1 = part[rowgrp][0][lane][4 + q] + part[rowgrp][1][lane][4 + q] + b1b;
    p[q] = fmaxf(u0, 0.f) * w2a + fmaxf(u1, 0.f) * w2b;
  }
#pragma unroll
  for (int m = 1; m < 16; m <<= 1) {
#pragma unroll
    for (int q = 0; q < 4; ++q) p[q] += __shfl_xor(p[q], m);
  }
  if (lr == 0) {
    const float b2 = h2b[0];
#pragma unroll
    for (int q = 0; q < 4; ++q) {
      const int row = m0 + (lane >> 4) * 4 + q;
      hbuf[(size_t)row * NSTEP + tstep] = 1.f / (1.f + expf(-(p[q] + b2)));
    }
  }
}

// ---------------- PonderNet recurrence (per-row scalar) ----------------------
__global__ void ponder_rec(const float* __restrict__ hbuf,
                           float* __restrict__ out_hd, float* __restrict__ out_es,
                           float* __restrict__ out_cu, float* __restrict__ wsum) {
  const int row = blockIdx.x * 256 + threadIdx.x;
  const float* hp = hbuf + (size_t)row * NSTEP;
  float c = 0.f, ps = 0.f, es = 0.f;
  float hd[NSTEP];
#pragma unroll
  for (int t = 0; t < NSTEP; ++t) {
    const float halt = hp[t];
    const float pt = halt * expf(c);
    float w;
    if (t == NSTEP - 1) {
      w = pt + fmaxf(1.f - (ps + pt), 0.f);
    } else {
      w = pt;
      c += logf(1.f - halt + 1e-8f);
      ps += pt;
    }
    es += w * (float)(t + 1);
    hd[t] = w;
  }
#pragma unroll
  for (int t = 0; t < NSTEP; ++t) out_hd[(size_t)row * NSTEP + t] = hd[t];
  out_es[row] = es;
  out_cu[row] = es * (1.0f / NSTEP);
  wsum[row] = ps + hd[NSTEP - 1];
}

// ---------------- final weighted sum: hw = sum_t w_t * h_t -------------------
__global__ void hw_final(const __hip_bfloat16* __restrict__ hstack,  // [11][B][H], slots 1..10
                         const float* __restrict__ out_hd,           // [B][10]
                         __hip_bfloat16* __restrict__ hwb) {
  const int t = threadIdx.x;
  const int row = blockIdx.x * 4 + (t >> 6);
  const int c0 = (t & 63) * 16;
  const float* hd = out_hd + (size_t)row * NSTEP;
  float accv[16] = {};
#pragma unroll
  for (int s = 0; s < NSTEP; ++s) {
    const float w = hd[s];
    const short8* p = (const short8*)(hstack + ((size_t)(s + 1) * B_ + row) * H_ + c0);
    short8 a0 = p[0], a1 = p[1];
#pragma unroll
    for (int q = 0; q < 8; ++q) accv[q] += w * b2f(a0[q]);
#pragma unroll
    for (int q = 0; q < 8; ++q) accv[8 + q] += w * b2f(a1[q]);
  }
  short8 r0, r1;
#pragma unroll
  for (int q = 0; q < 8; ++q) { r0[q] = (short)f2us(accv[q]); r1[q] = (short)f2us(accv[8 + q]); }
  short8* dst = (short8*)(hwb + (size_t)row * H_ + c0);
  dst[0] = r0; dst[1] = r1;
}

// ---------------- softmax + confidence ---------------------------------------
__global__ void finalize(const float* __restrict__ wl, const float* __restrict__ es,
                         float* __restrict__ probs, float* __restrict__ conf,
                         float* __restrict__ sconf) {
  const int row = blockIdx.x, t = threadIdx.x;
  __shared__ float red[4], red2[4];
  float4 v = make_float4(-1e30f, -1e30f, -1e30f, -1e30f);
  float m = -1e30f;
  if (t < 250) {
    v = ((const float4*)(wl + (size_t)row * C_))[t];
    m = fmaxf(fmaxf(v.x, v.y), fmaxf(v.z, v.w));
  }
#pragma unroll
  for (int off = 32; off; off >>= 1) m = fmaxf(m, __shfl_down(m, off));
  if ((t & 63) == 0) red[t >> 6] = m;
  __syncthreads();
  m = fmaxf(fmaxf(red[0], red[1]), fmaxf(red[2], red[3]));
  float4 e = make_float4(0.f, 0.f, 0.f, 0.f);
  float s = 0.f;
  if (t < 250) {
    e.x = expf(v.x - m); e.y = expf(v.y - m); e.z = expf(v.z - m); e.w = expf(v.w - m);
    s = e.x + e.y + e.z + e.w;
  }
#pragma unroll
  for (int off = 32; off; off >>= 1) s += __shfl_down(s, off);
  if ((t & 63) == 0) red2[t >> 6] = s;
  __syncthreads();
  s = red2[0] + red2[1] + red2[2] + red2[3];
  const float inv = 1.0f / s;
  if (t < 250)
    ((float4*)(probs + (size_t)row * C_))[t] = make_float4(e.x * inv, e.y * inv, e.z * inv, e.w * inv);
  if (t == 0) {
    sconf[row] = inv;
    conf[row] = 0.7f * inv + 0.3f * (1.0f - es[row] * (1.0f / NSTEP));
  }
}

// ---------------- host orchestration -----------------------------------------
extern "C" void kernel_launch(void* const* d_in, const int* in_sizes, int n_in,
                              void* d_out, int out_size, void* d_ws, size_t ws_size,
                              hipStream_t stream) {
  (void)in_sizes; (void)n_in; (void)out_size; (void)ws_size;
  const float* x     = (const float*)d_in[0];
  const float* enc_W = (const float*)d_in[1];
  const float* enc_b = (const float*)d_in[2];
  const float* ln_g  = (const float*)d_in[3];
  const float* ln_b  = (const float*)d_in[4];
  const float* W_ih  = (const float*)d_in[5];
  const float* W_hh  = (const float*)d_in[6];
  const float* b_ih  = (const float*)d_in[7];
  const float* b_hh  = (const float*)d_in[8];
  const float* cls_W = (const float*)d_in[9];
  const float* cls_b = (const float*)d_in[10];
  const float* h1_W  = (const float*)d_in[11];
  const float* h1_b  = (const float*)d_in[12];
  const float* h2_W  = (const float*)d_in[13];
  const float* h2_b  = (const float*)d_in[14];

  char* wsp = (char*)d_ws;
  auto carve = [&](size_t n) { char* p = wsp; wsp += (n + 255) & ~(size_t)255; return p; };
  __hip_bfloat16* Wc4b   = (__hip_bfloat16*)carve((size_t)4 * H_ * H_ * 2);
  __hip_bfloat16* clsWb  = (__hip_bfloat16*)carve((size_t)1024 * 1024 * 2);
  __hip_bfloat16* encWb  = (__hip_bfloat16*)carve((size_t)H_ * D_ * 2);
  __hip_bfloat16* h1Wb   = (__hip_bfloat16*)carve((size_t)32 * H_ * 2);
  __hip_bfloat16* hstack = (__hip_bfloat16*)carve((size_t)(NSTEP + 1) * B_ * H_ * 2);
  float* wsum = (float*)carve((size_t)B_ * 4);
  float* hbuf = (float*)carve((size_t)B_ * NSTEP * 4);

  const size_t SLOT = (size_t)B_ * H_;  // elements per hstack slot
  float* z            = (float*)(hstack + SLOT);        // slots 1-2 (32MB fp32)
  __hip_bfloat16* xb  = hstack + 3 * SLOT;              // slots 3-4 (32MB bf16)
  __hip_bfloat16* hwb = hstack;                         // slot 0, reused at end

  float* out = (float*)d_out;
  float* out_wl    = out;
  float* out_probs = out + (size_t)B_ * C_;
  float* out_conf  = out + (size_t)2 * B_ * C_;
  float* out_sconf = out_conf + B_;
  float* out_es    = out_sconf + B_;
  float* out_hd    = out_es + B_;
  float* out_cu    = out_hd + (size_t)B_ * NSTEP;

  dim3 blk(256);
  // merged conversions (x, encW, gates, clsW-pad, h1W) in one launch
  {
    const int total = B_ * D_ / 4 + H_ * D_ / 4 + H_ * H_ + 1024 * 1024 / 4 + 32 * H_ / 4;
    cvt_all<<<(total + 255) / 256, blk, 0, stream>>>(
        x, enc_W, W_ih, W_hh, cls_W, h1_W, xb, encWb, Wc4b, clsWb, h1Wb);
  }

  // encoder: GEMM -> z (fp32, slots 1-2), LN+GELU -> h0 (slot 0, bf16)
  gemm_bt<0><<<dim3(B_ / 128, H_ / 128), blk, 0, stream>>>(
      xb, D_, encWb, D_, D_, enc_b, z, H_, H_, nullptr);
  ln_gelu<<<B_, blk, 0, stream>>>(z, ln_g, ln_b, hstack);

  // 10 GRU steps, back-to-back
  for (int step = 0; step < NSTEP; ++step) {
    const __hip_bfloat16* hprev = hstack + (size_t)step * SLOT;
    __hip_bfloat16* hnext = hstack + (size_t)(step + 1) * SLOT;
    gemm_gru<<<dim3(B_ / 128, H_ / 64), blk, 0, stream>>>(
        hprev, Wc4b, b_ih, b_hh, hnext);
  }

  // batched halt MLP over all steps, then the tiny sequential recurrence
  halt_mlp_all<<<dim3(B_ / 32, NSTEP), blk, 0, stream>>>(
      hstack, h1Wb, h1_b, h2_W, h2_b, hbuf);
  ponder_rec<<<B_ / 256, blk, 0, stream>>>(hbuf, out_hd, out_es, out_cu, wsum);

  // hw = sum_t w_t h_t  (reads slots 1..10, writes slot 0)
  hw_final<<<B_ / 4, blk, 0, stream>>>(hstack, out_hd, hwb);

  // weighted logits: hw @ cls_W^T + cls_b * wsum
  gemm_bt<1><<<dim3(B_ / 128, 1024 / 128), blk, 0, stream>>>(
      hwb, H_, clsWb, H_, H_, cls_b, out_wl, C_, C_, wsum);

  finalize<<<B_, blk, 0, stream>>>(out_wl, out_es, out_probs, out_conf, out_sconf);
}